// Round 1
// baseline (1403.212 us; speedup 1.0000x reference)
//
#include <hip/hip_runtime.h>
#include <math.h>

#define Bsz  2048
#define Ccnt 100000
#define Dd   128

// ---- order-preserving float <-> uint encoding for atomicMax ----
static __device__ __forceinline__ unsigned int enc_f32(float f) {
    unsigned int u = __float_as_uint(f);
    return (u & 0x80000000u) ? ~u : (u | 0x80000000u);
}
static __device__ __forceinline__ float dec_f32(unsigned int u) {
    unsigned int b = (u & 0x80000000u) ? (u & 0x7fffffffu) : ~u;
    return __uint_as_float(b);
}

// ---- margin max kernel ----
// block tile: 128 samples x 128 classes; K=128 staged in two 64-wide halves.
// 256 threads as 16x16; each thread computes an 8x8 micro-tile (spread
// mapping i*16+sy / j*16+sx -> 2-way-max LDS bank aliasing, which is free).
#define SMP_TILE 128
#define CLS_TILE 128
#define KHALF    64
#define LDW      68   // 64 + 4 pad floats; 68*4=272 B keeps 16B alignment

__global__ __launch_bounds__(256, 2) void margin_max_kernel(
    const int* __restrict__ labels,
    const float* __restrict__ wnorm,
    unsigned int* __restrict__ maxbuf)
{
    __shared__ float Qs[SMP_TILE * LDW];
    __shared__ float Ws[CLS_TILE * LDW];

    const int tid   = threadIdx.x;
    const int cbase = blockIdx.x * CLS_TILE;
    const int sbase = blockIdx.y * SMP_TILE;
    const int sy    = tid >> 4;   // 0..15 sample group
    const int sx    = tid & 15;   // 0..15 class group

    float acc[8][8];
#pragma unroll
    for (int i = 0; i < 8; ++i)
#pragma unroll
        for (int j = 0; j < 8; ++j) acc[i][j] = 0.f;

    for (int h = 0; h < 2; ++h) {
        // cooperative staging of K-half h: 256 rows (128 Q + 128 W) x 64 floats
#pragma unroll
        for (int it = 0; it < 16; ++it) {
            int j   = it * 256 + tid;
            int row = j >> 4;           // 0..255
            int c4  = (j & 15) << 2;    // float col within half
            if (row < SMP_TILE) {
                int lab = labels[sbase + row];
                if (lab < 0) lab = 0;
                float4 v = *reinterpret_cast<const float4*>(
                    wnorm + (size_t)lab * Dd + h * KHALF + c4);
                *reinterpret_cast<float4*>(&Qs[row * LDW + c4]) = v;
            } else {
                int r = row - SMP_TILE;
                int c = cbase + r;
                float4 v = make_float4(0.f, 0.f, 0.f, 0.f);
                if (c < Ccnt)
                    v = *reinterpret_cast<const float4*>(
                        wnorm + (size_t)c * Dd + h * KHALF + c4);
                *reinterpret_cast<float4*>(&Ws[r * LDW + c4]) = v;
            }
        }
        __syncthreads();

#pragma unroll
        for (int k4 = 0; k4 < KHALF / 4; ++k4) {
            float4 q[8], w[8];
#pragma unroll
            for (int i = 0; i < 8; ++i)
                q[i] = *reinterpret_cast<const float4*>(
                    &Qs[(i * 16 + sy) * LDW + k4 * 4]);
#pragma unroll
            for (int jj = 0; jj < 8; ++jj)
                w[jj] = *reinterpret_cast<const float4*>(
                    &Ws[(jj * 16 + sx) * LDW + k4 * 4]);
#pragma unroll
            for (int i = 0; i < 8; ++i)
#pragma unroll
                for (int jj = 0; jj < 8; ++jj) {
                    acc[i][jj] = fmaf(q[i].x, w[jj].x, acc[i][jj]);
                    acc[i][jj] = fmaf(q[i].y, w[jj].y, acc[i][jj]);
                    acc[i][jj] = fmaf(q[i].z, w[jj].z, acc[i][jj]);
                    acc[i][jj] = fmaf(q[i].w, w[jj].w, acc[i][jj]);
                }
        }
        __syncthreads();
    }

    // clamp, mask self-class & OOB classes, per-sample max over classes
    int labv[8];
#pragma unroll
    for (int i = 0; i < 8; ++i) labv[i] = labels[sbase + i * 16 + sy];

    float m[8];
#pragma unroll
    for (int i = 0; i < 8; ++i) {
        float mi = -3.0f;
#pragma unroll
        for (int jj = 0; jj < 8; ++jj) {
            int c   = cbase + jj * 16 + sx;
            float v = acc[i][jj];
            v = fminf(fmaxf(v, -1.f), 1.f);
            if (c >= Ccnt || c == labv[i]) v = -3.0f;
            mi = fmaxf(mi, v);
        }
        m[i] = mi;
    }
    // reduce across the 16 lanes sharing sy (consecutive lanes)
#pragma unroll
    for (int off = 1; off < 16; off <<= 1) {
#pragma unroll
        for (int i = 0; i < 8; ++i)
            m[i] = fmaxf(m[i], __shfl_xor(m[i], off, 64));
    }
    if (sx == 0) {
#pragma unroll
        for (int i = 0; i < 8; ++i)
            atomicMax(&maxbuf[sbase + i * 16 + sy], enc_f32(m[i]));
    }
}

// ---- elementwise scale: out = logits * 64 ----
__global__ __launch_bounds__(256) void scale_kernel(
    const float4* __restrict__ in, float4* __restrict__ out, int n4)
{
    int idx    = blockIdx.x * 256 + threadIdx.x;
    int stride = gridDim.x * 256;
    for (int i = idx; i < n4; i += stride) {
        float4 v = in[i];
        v.x *= 64.f; v.y *= 64.f; v.z *= 64.f; v.w *= 64.f;
        out[i] = v;
    }
}

// ---- per-sample target fixup ----
__global__ void fixup_kernel(const float* __restrict__ logits,
                             const int* __restrict__ labels,
                             const unsigned int* __restrict__ maxbuf,
                             float* __restrict__ out)
{
    int b = blockIdx.x * blockDim.x + threadIdx.x;
    if (b >= Bsz) return;
    int lab = labels[b];
    if (lab < 0) return;  // invalid label: plain scale already correct
    float mx = dec_f32(maxbuf[b]);
    mx = fminf(fmaxf(mx, -1.f), 1.f);
    float theta  = acosf(mx);
    float d      = theta - 1.0f;                         // K1
    float smooth = 0.012f / powf(1.0f + fabsf(d) * 20.0f, 1.1f); // 0.03*K3
    float margin = fmaxf(d, 0.f) * 0.1f + 0.4f + smooth; // K2, K3
    size_t off = (size_t)b * Ccnt + lab;
    float x = logits[off];
    out[off] = cosf(acosf(x) + margin) * 64.0f;          // S
}

extern "C" void kernel_launch(void* const* d_in, const int* in_sizes, int n_in,
                              void* d_out, int out_size, void* d_ws, size_t ws_size,
                              hipStream_t stream)
{
    const float* logits = (const float*)d_in[0];
    const int*   labels = (const int*)d_in[1];
    const float* wnorm  = (const float*)d_in[2];
    float* out = (float*)d_out;
    unsigned int* maxbuf = (unsigned int*)d_ws;

    // reset the running-max buffer (encoded 0 < enc(-1) <= any real max)
    hipMemsetAsync(maxbuf, 0, Bsz * sizeof(unsigned int), stream);

    dim3 mgrid((Ccnt + CLS_TILE - 1) / CLS_TILE, Bsz / SMP_TILE);
    margin_max_kernel<<<mgrid, 256, 0, stream>>>(labels, wnorm, maxbuf);

    int n4 = Bsz * (Ccnt / 4);
    scale_kernel<<<2048, 256, 0, stream>>>(
        (const float4*)logits, (float4*)out, n4);

    fixup_kernel<<<(Bsz + 255) / 256, 256, 0, stream>>>(
        logits, labels, maxbuf, out);
}

// Round 2
// 597.256 us; speedup vs baseline: 2.3494x; 2.3494x over previous
//
#include <hip/hip_runtime.h>
#include <math.h>

#define Bsz   2048
#define Ccnt  100000
#define Dd    128
#define CT    128          // classes per block
#define NCHUNK (Bsz / 32)  // 64 sample chunks of 32

typedef short  bf16x8  __attribute__((ext_vector_type(8)));
typedef float  f32x16  __attribute__((ext_vector_type(16)));

// ---- order-preserving float <-> uint encoding for atomicMax ----
static __device__ __forceinline__ unsigned int enc_f32(float f) {
    unsigned int u = __float_as_uint(f);
    return (u & 0x80000000u) ? ~u : (u | 0x80000000u);
}
static __device__ __forceinline__ float dec_f32(unsigned int u) {
    unsigned int b = (u & 0x80000000u) ? (u & 0x7fffffffu) : ~u;
    return __uint_as_float(b);
}
// fp32 -> bf16 round-to-nearest-even (no NaN handling needed here)
static __device__ __forceinline__ unsigned short f2bf(float f) {
    unsigned int u = __float_as_uint(f);
    unsigned int r = ((u >> 16) & 1u) + 0x7fffu;
    return (unsigned short)((u + r) >> 16);
}

// ---- prep: Qbf[b][d] = bf16(wnorm[labels[b]][d]) ----
__global__ __launch_bounds__(256) void prep_kernel(
    const int* __restrict__ labels,
    const float* __restrict__ wnorm,
    unsigned short* __restrict__ qbf)
{
    int tid = blockIdx.x * 256 + threadIdx.x;   // 2048*16 = 32768 threads
    int b   = tid >> 4;
    int c8  = (tid & 15) << 3;                  // 8 floats per thread
    if (b >= Bsz) return;
    int lab = labels[b];
    if (lab < 0) lab = 0;
    const float* src = wnorm + (size_t)lab * Dd + c8;
    float4 u = *reinterpret_cast<const float4*>(src);
    float4 v = *reinterpret_cast<const float4*>(src + 4);
    unsigned short o[8] = { f2bf(u.x), f2bf(u.y), f2bf(u.z), f2bf(u.w),
                            f2bf(v.x), f2bf(v.y), f2bf(v.z), f2bf(v.w) };
    *reinterpret_cast<bf16x8*>(qbf + (size_t)b * Dd + c8) =
        *reinterpret_cast<bf16x8*>(o);
}

// ---- margin max via bf16 MFMA ----
// Block: 256 threads = 4 waves; block owns 128 classes, wave owns 32.
// Wave holds its 32 W rows as MFMA A-fragments in registers (loaded once),
// loops 64 sample-chunks of 32 reading Q B-fragments from L2-resident qbf.
__global__ __launch_bounds__(256) void margin_mfma_kernel(
    const int* __restrict__ labels,
    const float* __restrict__ wnorm,
    const unsigned short* __restrict__ qbf,
    unsigned int* __restrict__ maxbuf)
{
    __shared__ unsigned int smax[Bsz];
    for (int i = threadIdx.x; i < Bsz; i += 256) smax[i] = 0u;
    __syncthreads();

    const int wave  = threadIdx.x >> 6;
    const int lane  = threadIdx.x & 63;
    const int h     = lane >> 5;     // K-half (0/1)
    const int lm    = lane & 31;
    const int cbase = blockIdx.x * CT + wave * 32;
    const int cls   = cbase + lm;    // this lane's A-operand row (class)
    const bool cvalid = cls < Ccnt;

    // load & convert this lane's W row into 8 A-fragments (held all kernel)
    bf16x8 afr[8];
    {
        const float* wr = wnorm + (size_t)(cvalid ? cls : 0) * Dd + h * 8;
#pragma unroll
        for (int t = 0; t < 8; ++t) {
            float4 u = *reinterpret_cast<const float4*>(wr + t * 16);
            float4 v = *reinterpret_cast<const float4*>(wr + t * 16 + 4);
            if (!cvalid) { u = make_float4(0,0,0,0); v = make_float4(0,0,0,0); }
            unsigned short o[8] = { f2bf(u.x), f2bf(u.y), f2bf(u.z), f2bf(u.w),
                                    f2bf(v.x), f2bf(v.y), f2bf(v.z), f2bf(v.w) };
            afr[t] = *reinterpret_cast<bf16x8*>(o);
        }
    }

    const int base_c = cbase + 4 * h;  // acc-reg class = base_c + rowmap(r)

    for (int ch = 0; ch < NCHUNK; ++ch) {
        const int s = ch * 32 + lm;   // this lane's B-operand col (sample)
        const unsigned short* qr = qbf + (size_t)s * Dd + h * 8;
        bf16x8 bfr[8];
#pragma unroll
        for (int t = 0; t < 8; ++t)
            bfr[t] = *reinterpret_cast<const bf16x8*>(qr + t * 16);

        f32x16 acc = {};
#pragma unroll
        for (int t = 0; t < 8; ++t)
            acc = __builtin_amdgcn_mfma_f32_32x32x16_bf16(afr[t], bfr[t], acc, 0, 0, 0);

        const int lab = labels[s];
        const int rel = lab - base_c;       // self-class relative row
        const int lim = Ccnt - base_c;      // OOB threshold on rowmap

        float m = -3.0f;
#pragma unroll
        for (int r = 0; r < 16; ++r) {
            const int row = (r & 3) + 8 * (r >> 2);  // + 4h folded into base_c
            float v = acc[r];
            if (rel == row || row >= lim) v = -3.0f;
            m = fmaxf(m, v);
        }
        m = fmaxf(m, __shfl_xor(m, 32));    // combine the two K-half lane sets
        if (lane < 32) atomicMax(&smax[s], enc_f32(m));
    }
    __syncthreads();
    for (int i = threadIdx.x; i < Bsz; i += 256)
        atomicMax(&maxbuf[i], smax[i]);
}

// ---- elementwise scale: out = logits * 64 ----
__global__ __launch_bounds__(256) void scale_kernel(
    const float4* __restrict__ in, float4* __restrict__ out, int n4)
{
    int idx    = blockIdx.x * 256 + threadIdx.x;
    int stride = gridDim.x * 256;
    for (int i = idx; i < n4; i += stride) {
        float4 v = in[i];
        v.x *= 64.f; v.y *= 64.f; v.z *= 64.f; v.w *= 64.f;
        out[i] = v;
    }
}

// ---- per-sample target fixup ----
__global__ void fixup_kernel(const float* __restrict__ logits,
                             const int* __restrict__ labels,
                             const unsigned int* __restrict__ maxbuf,
                             float* __restrict__ out)
{
    int b = blockIdx.x * blockDim.x + threadIdx.x;
    if (b >= Bsz) return;
    int lab = labels[b];
    if (lab < 0) return;  // invalid label: plain scale already correct
    float mx = dec_f32(maxbuf[b]);
    mx = fminf(fmaxf(mx, -1.f), 1.f);
    float theta  = acosf(mx);
    float d      = theta - 1.0f;                         // K1
    float smooth = 0.012f / powf(1.0f + fabsf(d) * 20.0f, 1.1f); // 0.03*K3
    float margin = fmaxf(d, 0.f) * 0.1f + 0.4f + smooth; // K2, K3
    size_t off = (size_t)b * Ccnt + lab;
    float x = logits[off];
    out[off] = cosf(acosf(x) + margin) * 64.0f;          // S
}

extern "C" void kernel_launch(void* const* d_in, const int* in_sizes, int n_in,
                              void* d_out, int out_size, void* d_ws, size_t ws_size,
                              hipStream_t stream)
{
    const float* logits = (const float*)d_in[0];
    const int*   labels = (const int*)d_in[1];
    const float* wnorm  = (const float*)d_in[2];
    float* out = (float*)d_out;

    unsigned int*   maxbuf = (unsigned int*)d_ws;            // 8 KB
    unsigned short* qbf    = (unsigned short*)((char*)d_ws + 8192); // 512 KB

    // reset running-max buffer (encoded 0 < enc(any real value))
    hipMemsetAsync(maxbuf, 0, Bsz * sizeof(unsigned int), stream);

    prep_kernel<<<(Bsz * (Dd / 8) + 255) / 256, 256, 0, stream>>>(
        labels, wnorm, qbf);

    margin_mfma_kernel<<<(Ccnt + CT - 1) / CT, 256, 0, stream>>>(
        labels, wnorm, qbf, maxbuf);

    int n4 = Bsz * (Ccnt / 4);
    scale_kernel<<<2048, 256, 0, stream>>>(
        (const float4*)logits, (float4*)out, n4);

    fixup_kernel<<<(Bsz + 255) / 256, 256, 0, stream>>>(
        logits, labels, maxbuf, out);
}

// Round 4
// 596.400 us; speedup vs baseline: 2.3528x; 1.0014x over previous
//
#include <hip/hip_runtime.h>
#include <math.h>

#define Bsz   2048
#define Ccnt  100000
#define Dd    128
#define CT    128          // classes per block
#define NCHUNK (Bsz / 32)  // 64 sample chunks of 32

typedef short  bf16x8  __attribute__((ext_vector_type(8)));
typedef float  f32x16  __attribute__((ext_vector_type(16)));
typedef float  f32x4   __attribute__((ext_vector_type(4)));

// ---- order-preserving float <-> uint encoding for atomicMax ----
static __device__ __forceinline__ unsigned int enc_f32(float f) {
    unsigned int u = __float_as_uint(f);
    return (u & 0x80000000u) ? ~u : (u | 0x80000000u);
}
static __device__ __forceinline__ float dec_f32(unsigned int u) {
    unsigned int b = (u & 0x80000000u) ? (u & 0x7fffffffu) : ~u;
    return __uint_as_float(b);
}
// fp32 -> bf16 round-to-nearest-even
static __device__ __forceinline__ unsigned short f2bf(float f) {
    unsigned int u = __float_as_uint(f);
    unsigned int r = ((u >> 16) & 1u) + 0x7fffu;
    return (unsigned short)((u + r) >> 16);
}

// ---- prep: Qbf[b][d] = bf16(wnorm[labels[b]][d]); also zero maxbuf ----
__global__ __launch_bounds__(256) void prep_kernel(
    const int* __restrict__ labels,
    const float* __restrict__ wnorm,
    unsigned short* __restrict__ qbf,
    unsigned int* __restrict__ maxbuf)
{
    int tid = blockIdx.x * 256 + threadIdx.x;   // 32768 threads
    if (tid < Bsz) maxbuf[tid] = 0u;            // reset running-max (enc space)
    int b   = tid >> 4;
    int c8  = (tid & 15) << 3;                  // 8 floats per thread
    if (b >= Bsz) return;
    int lab = labels[b];
    if (lab < 0) lab = 0;
    const float* src = wnorm + (size_t)lab * Dd + c8;
    float4 u = *reinterpret_cast<const float4*>(src);
    float4 v = *reinterpret_cast<const float4*>(src + 4);
    unsigned short o[8] = { f2bf(u.x), f2bf(u.y), f2bf(u.z), f2bf(u.w),
                            f2bf(v.x), f2bf(v.y), f2bf(v.z), f2bf(v.w) };
    *reinterpret_cast<bf16x8*>(qbf + (size_t)b * Dd + c8) =
        *reinterpret_cast<bf16x8*>(o);
}

// ---- margin max via bf16 MFMA: 2 independent K-chains + next-chunk prefetch
__global__ __launch_bounds__(256, 3) void margin_mfma_kernel(
    const int* __restrict__ labels,
    const float* __restrict__ wnorm,
    const unsigned short* __restrict__ qbf,
    unsigned int* __restrict__ maxbuf)
{
    __shared__ unsigned int smax[Bsz];
    for (int i = threadIdx.x; i < Bsz; i += 256) smax[i] = 0u;
    __syncthreads();

    const int wave  = threadIdx.x >> 6;
    const int lane  = threadIdx.x & 63;
    const int h     = lane >> 5;     // K-half (0/1)
    const int lm    = lane & 31;
    const int cbase = blockIdx.x * CT + wave * 32;
    const int cls   = cbase + lm;    // this lane's A-operand row (class)
    const bool cvalid = cls < Ccnt;

    // load & convert this lane's W row into 8 A-fragments (held all kernel)
    bf16x8 afr[8];
    {
        const float* wr = wnorm + (size_t)(cvalid ? cls : 0) * Dd + h * 8;
#pragma unroll
        for (int t = 0; t < 8; ++t) {
            float4 u = *reinterpret_cast<const float4*>(wr + t * 16);
            float4 v = *reinterpret_cast<const float4*>(wr + t * 16 + 4);
            if (!cvalid) { u = make_float4(0,0,0,0); v = make_float4(0,0,0,0); }
            unsigned short o[8] = { f2bf(u.x), f2bf(u.y), f2bf(u.z), f2bf(u.w),
                                    f2bf(v.x), f2bf(v.y), f2bf(v.z), f2bf(v.w) };
            afr[t] = *reinterpret_cast<bf16x8*>(o);
        }
    }

    const int base_c = cbase + 4 * h;  // acc-reg class = base_c + rowmap(r)

    // prefetch chunk 0 B-fragments
    bf16x8 bcur[8];
    {
        const unsigned short* qr = qbf + (size_t)lm * Dd + h * 8;
#pragma unroll
        for (int t = 0; t < 8; ++t)
            bcur[t] = *reinterpret_cast<const bf16x8*>(qr + t * 16);
    }

    for (int ch = 0; ch < NCHUNK; ++ch) {
        const int s = ch * 32 + lm;   // this lane's B-operand col (sample)

        // issue next chunk's loads before the MFMA cluster
        bf16x8 bnxt[8];
        if (ch + 1 < NCHUNK) {
            const unsigned short* qr = qbf + (size_t)(s + 32) * Dd + h * 8;
#pragma unroll
            for (int t = 0; t < 8; ++t)
                bnxt[t] = *reinterpret_cast<const bf16x8*>(qr + t * 16);
        }

        f32x16 acc0 = {}, acc1 = {};
#pragma unroll
        for (int t = 0; t < 8; t += 2) {
            acc0 = __builtin_amdgcn_mfma_f32_32x32x16_bf16(afr[t],     bcur[t],     acc0, 0, 0, 0);
            acc1 = __builtin_amdgcn_mfma_f32_32x32x16_bf16(afr[t + 1], bcur[t + 1], acc1, 0, 0, 0);
        }

        const int lab = labels[s];
        const int rel = lab - base_c;       // self-class relative row
        const int lim = Ccnt - base_c;      // OOB threshold on rowmap

        float m = -3.0f;
#pragma unroll
        for (int r = 0; r < 16; ++r) {
            const int row = (r & 3) + 8 * (r >> 2);  // + 4h folded into base_c
            float v = acc0[r] + acc1[r];
            if (rel == row || row >= lim) v = -3.0f;
            m = fmaxf(m, v);
        }
        m = fmaxf(m, __shfl_xor(m, 32));    // combine the two K-half lane sets
        if (lane < 32) atomicMax(&smax[s], enc_f32(m));

#pragma unroll
        for (int t = 0; t < 8; ++t) bcur[t] = bnxt[t];
    }
    __syncthreads();
    for (int i = threadIdx.x; i < Bsz; i += 256)
        atomicMax(&maxbuf[i], smax[i]);
}

// ---- elementwise scale: out = logits * 64 (nontemporal, x2 unroll) ----
__global__ __launch_bounds__(256) void scale_kernel(
    const f32x4* __restrict__ in, f32x4* __restrict__ out, int n4)
{
    int i0     = (blockIdx.x * 256 + threadIdx.x) * 2;
    int stride = gridDim.x * 512;
    for (int i = i0; i < n4; i += stride) {
        f32x4 a = __builtin_nontemporal_load(in + i);
        f32x4 b = __builtin_nontemporal_load(in + i + 1);   // n4 is even
        a *= 64.f;
        b *= 64.f;
        __builtin_nontemporal_store(a, out + i);
        __builtin_nontemporal_store(b, out + i + 1);
    }
}

// ---- per-sample target fixup ----
__global__ void fixup_kernel(const float* __restrict__ logits,
                             const int* __restrict__ labels,
                             const unsigned int* __restrict__ maxbuf,
                             float* __restrict__ out)
{
    int b = blockIdx.x * blockDim.x + threadIdx.x;
    if (b >= Bsz) return;
    int lab = labels[b];
    if (lab < 0) return;  // invalid label: plain scale already correct
    float mx = dec_f32(maxbuf[b]);
    mx = fminf(fmaxf(mx, -1.f), 1.f);
    float theta  = acosf(mx);
    float d      = theta - 1.0f;                         // K1
    float smooth = 0.012f / powf(1.0f + fabsf(d) * 20.0f, 1.1f); // 0.03*K3
    float margin = fmaxf(d, 0.f) * 0.1f + 0.4f + smooth; // K2, K3
    size_t off = (size_t)b * Ccnt + lab;
    float x = logits[off];
    out[off] = cosf(acosf(x) + margin) * 64.0f;          // S
}

extern "C" void kernel_launch(void* const* d_in, const int* in_sizes, int n_in,
                              void* d_out, int out_size, void* d_ws, size_t ws_size,
                              hipStream_t stream)
{
    const float* logits = (const float*)d_in[0];
    const int*   labels = (const int*)d_in[1];
    const float* wnorm  = (const float*)d_in[2];
    float* out = (float*)d_out;

    unsigned int*   maxbuf = (unsigned int*)d_ws;                   // 8 KB
    unsigned short* qbf    = (unsigned short*)((char*)d_ws + 8192); // 512 KB

    prep_kernel<<<(Bsz * (Dd / 8) + 255) / 256, 256, 0, stream>>>(
        labels, wnorm, qbf, maxbuf);

    margin_mfma_kernel<<<(Ccnt + CT - 1) / CT, 256, 0, stream>>>(
        labels, wnorm, qbf, maxbuf);

    int n4 = Bsz * (Ccnt / 4);
    scale_kernel<<<2048, 256, 0, stream>>>(
        (const f32x4*)logits, (f32x4*)out, n4);

    fixup_kernel<<<(Bsz + 255) / 256, 256, 0, stream>>>(
        logits, labels, maxbuf, out);
}